// Round 10
// baseline (176.190 us; speedup 1.0000x reference)
//
#include <hip/hip_runtime.h>
#include <hip/hip_bf16.h>

// Problem constants
#define Nn   32
#define Ee   512
#define DIN  300
#define DOUT 300
#define NT   4
#define QD   300
#define SLOPE 0.2f
#define ROWS 32   // rows per tile in score/pv kernels
#define CPAD 320  // padded d-dim for hmT (20 MFMA n-tiles of 16)

typedef __attribute__((ext_vector_type(8))) short bf16x8;
typedef __attribute__((ext_vector_type(4))) float f32x4;
typedef __attribute__((ext_vector_type(4))) unsigned short u16x4;

__device__ inline unsigned short f2bf(float x) {
    __hip_bfloat16 h = __float2bfloat16(x);   // RNE
    return *reinterpret_cast<unsigned short*>(&h);
}
__device__ inline float bf2f(unsigned short u) {
    __hip_bfloat16 h = *reinterpret_cast<__hip_bfloat16*>(&u);
    return __bfloat162float(h);
}

// ---------------------------------------------------------------------------
// K0: prep. W3T split planes [c=320][k=320] (W3T[c][k] = W3[k][c], pad 0),
// zero UT planes [32][16][320], zero GT planes [4][64][320].
__global__ __launch_bounds__(256) void prep_kernel(
    const float* __restrict__ W3,          // (300, 300)  row k, col d
    unsigned short* __restrict__ W3T_hi,   // (320, 320)
    unsigned short* __restrict__ W3T_lo,
    unsigned short* __restrict__ UTh,      // (32, 16, 320)
    unsigned short* __restrict__ UTl,
    unsigned short* __restrict__ GTh,      // (4, 64, 320)
    unsigned short* __restrict__ GTl)
{
    int idx = blockIdx.x * 256 + threadIdx.x;   // grid 640 -> 163840 threads
    if (idx < 320 * 320) {
        int c = idx / 320, k = idx - c * 320;
        float v = (c < DOUT && k < DIN) ? W3[(size_t)k * DOUT + c] : 0.f;
        unsigned short h = f2bf(v);
        W3T_hi[idx] = h;
        W3T_lo[idx] = f2bf(v - bf2f(h));
    }
    if (idx < 32 * 16 * 320) { UTh[idx] = 0; UTl[idx] = 0; }
    if (idx < 4 * 64 * 320)  { GTh[idx] = 0; GTl[idx] = 0; }
}

// ---------------------------------------------------------------------------
// K1a: gates1 partial. t1p[z][i][n][j] = sum_{k in slab z} q[n][k]*W1[i][k][j]
// grid (75, NT, 4), block 256.
__global__ __launch_bounds__(256) void gates1_part_kernel(
    const float* __restrict__ q,    // (32, 300)
    const float* __restrict__ W1,   // (4, 300, 600)
    float* __restrict__ t1p)        // (4, 4, 32, 600)
{
    int i = blockIdx.y, z = blockIdx.z;
    int idx = blockIdx.x * 256 + threadIdx.x;   // 0..19199
    int n = idx / 600, j = idx - n * 600;
    const float* W1i = W1 + (size_t)i * QD * 600;
    const float* qn = q + n * QD;
    int k0 = z * 75;
    float a0 = 0.f;
    #pragma unroll 5
    for (int k = k0; k < k0 + 75; ++k)
        a0 += qn[k] * W1i[(size_t)k * 600 + j];
    t1p[((size_t)(z * NT + i) * Nn + n) * 600 + j] = a0;
}

// K1a-fin: t1 = relu(sum_z t1p). grid (75, NT).
__global__ __launch_bounds__(256) void gates1_fin_kernel(
    const float* __restrict__ t1p, float* __restrict__ t1)
{
    int i = blockIdx.y;
    int idx = blockIdx.x * 256 + threadIdx.x;
    size_t o = ((size_t)i * Nn) * 600 + idx;
    float s = t1p[o] + t1p[o + 76800] + t1p[o + 2 * 76800] + t1p[o + 3 * 76800];
    t1[o] = fmaxf(s, 0.f);
}

// ---------------------------------------------------------------------------
// K1b: gates2 partial. K=600, 4 slabs of 150.
__global__ __launch_bounds__(256) void gates2_part_kernel(
    const float* __restrict__ t1,   // (4, 32, 600)
    const float* __restrict__ W2,   // (4, 600, 600)
    float* __restrict__ gp)         // (4, 4, 32, 600)
{
    int i = blockIdx.y, z = blockIdx.z;
    int idx = blockIdx.x * 256 + threadIdx.x;
    int n = idx / 600, j = idx - n * 600;
    const float* W2i = W2 + (size_t)i * 600 * 600;
    const float* tn = t1 + ((size_t)i * Nn + n) * 600;
    int k0 = z * 150;
    float a0 = 0.f, a1 = 0.f;
    #pragma unroll 5
    for (int k = k0; k < k0 + 150; k += 2) {
        a0 += tn[k]     * W2i[(size_t)k * 600 + j];
        a1 += tn[k + 1] * W2i[(size_t)(k + 1) * 600 + j];
    }
    gp[((size_t)(z * NT + i) * Nn + n) * 600 + j] = a0 + a1;
}

// K1b-fin: gate = sigmoid(sum_z gp) * a  -> GT split planes [i][2n+s][d].
// grid (75, NT).
__global__ __launch_bounds__(256) void gates2_fin_kernel(
    const float* __restrict__ gp,
    const float* __restrict__ a,    // (4, 600)
    unsigned short* __restrict__ GTh,   // (4, 64, 320)
    unsigned short* __restrict__ GTl)
{
    int i = blockIdx.y;
    int idx = blockIdx.x * 256 + threadIdx.x;
    int n = idx / 600, j = idx - n * 600;
    size_t o = ((size_t)i * Nn + n) * 600 + j;
    float s = gp[o] + gp[o + 76800] + gp[o + 2 * 76800] + gp[o + 3 * 76800];
    float w = (1.f / (1.f + __expf(-s))) * a[(size_t)i * 600 + j];
    int s2 = (j >= DOUT) ? 1 : 0;
    int d = j - s2 * DOUT;
    int c = 2 * n + s2;
    size_t go = ((size_t)i * 64 + c) * 320 + d;
    unsigned short h = f2bf(w);
    GTh[go] = h;
    GTl[go] = f2bf(w - bf2f(h));
}

// ---------------------------------------------------------------------------
// K2: uvec via MFMA. Per type i: U = W[i](300k x 300d) @ GT[i]^T(300d x 64c).
// grid (5, NT), block 256 (4 waves). Wave wv: m-tile rows [mc*64+wv*16, +16).
// Output straight into UT planes (row n*16 + 2i+s, k-contiguous).
__global__ __launch_bounds__(256) void uvec_mfma_kernel(
    const float* __restrict__ W,            // (4, 300, 300)
    const unsigned short* __restrict__ GTh, // (4, 64, 320)
    const unsigned short* __restrict__ GTl,
    unsigned short* __restrict__ UTh,       // (32, 16, 320)
    unsigned short* __restrict__ UTl)
{
    int mc = blockIdx.x, i = blockIdx.y;
    int tid = threadIdx.x, wv = tid >> 6, lane = tid & 63;
    int g = lane >> 4, cr = lane & 15;
    int m0 = mc * 64 + wv * 16;
    int arow = m0 + cr;
    const float* wr = W + (size_t)i * DIN * DOUT
                        + (size_t)(arow < DIN ? arow : 0) * DOUT;

    f32x4 acc[4];
    #pragma unroll
    for (int nt = 0; nt < 4; ++nt) acc[nt] = (f32x4){0.f, 0.f, 0.f, 0.f};

    for (int ks = 0; ks < 10; ++ks) {
        int k0 = ks * 32 + 8 * g;
        float x8[8];
        if (ks < 9) {
            f32x4 v0 = *(const f32x4*)(wr + k0);
            f32x4 v1 = *(const f32x4*)(wr + k0 + 4);
            #pragma unroll
            for (int j = 0; j < 4; ++j) { x8[j] = v0[j]; x8[4 + j] = v1[j]; }
        } else {
            #pragma unroll
            for (int j = 0; j < 8; ++j) {
                int d = k0 + j;
                x8[j] = (d < DOUT) ? wr[d] : 0.f;
            }
        }
        bf16x8 ahi, alo;
        #pragma unroll
        for (int j = 0; j < 8; ++j) {
            unsigned short h = f2bf(x8[j]);
            ahi[j] = (short)h;
            alo[j] = (short)f2bf(x8[j] - bf2f(h));
        }
        #pragma unroll
        for (int nt = 0; nt < 4; ++nt) {
            size_t bo = ((size_t)i * 64 + nt * 16 + cr) * 320 + k0;
            bf16x8 bh = *(const bf16x8*)(GTh + bo);
            bf16x8 bl = *(const bf16x8*)(GTl + bo);
            acc[nt] = __builtin_amdgcn_mfma_f32_16x16x32_bf16(ahi, bh, acc[nt], 0, 0, 0);
            acc[nt] = __builtin_amdgcn_mfma_f32_16x16x32_bf16(ahi, bl, acc[nt], 0, 0, 0);
            acc[nt] = __builtin_amdgcn_mfma_f32_16x16x32_bf16(alo, bh, acc[nt], 0, 0, 0);
        }
    }

    int krow = m0 + 4 * g;   // 4-aligned; 300%4==0 so group fully in or out
    if (krow < DIN) {
        #pragma unroll
        for (int nt = 0; nt < 4; ++nt) {
            int c = nt * 16 + cr;
            int n = c >> 1, s = c & 1;
            size_t base = ((size_t)n * 16 + 2 * i + s) * 320 + krow;
            u16x4 h4, l4;
            #pragma unroll
            for (int q = 0; q < 4; ++q) {
                float v = acc[nt][q];
                unsigned short h = f2bf(v);
                h4[q] = h;
                l4[q] = f2bf(v - bf2f(h));
            }
            *(u16x4*)(UTh + base) = h4;
            *(u16x4*)(UTl + base) = l4;
        }
    }
}

// ---------------------------------------------------------------------------
// K4: MFMA hm GEMM + fused sdot (unchanged from round 8).
__global__ __launch_bounds__(256) void hm_mfma_kernel(
    const float* __restrict__ X,               // (16384, 300)
    const float* __restrict__ mask,            // (16384)
    const unsigned short* __restrict__ W3T_hi, // (320, 320)
    const unsigned short* __restrict__ W3T_lo,
    const unsigned short* __restrict__ UTh,    // (32, 16, 320)
    const unsigned short* __restrict__ UTl,
    unsigned short* __restrict__ hmT_hi,       // (32, CPAD, 512)
    unsigned short* __restrict__ hmT_lo,
    float* __restrict__ ssrc,                  // (4, 32, 512)
    float* __restrict__ sdst)
{
    int tid = threadIdx.x, wv = tid >> 6, lane = tid & 63;
    int g = lane >> 4, cr = lane & 15;
    size_t row0 = (size_t)blockIdx.x * 32;
    int n = (int)(row0 >> 9), j0 = (int)(row0 & 511);

    __shared__ float maskL[32];
    if (tid < 32) maskL[tid] = mask[row0 + tid];
    __syncthreads();

    f32x4 acc[5][2];
    f32x4 sacc[2];
    #pragma unroll
    for (int a = 0; a < 5; ++a)
        #pragma unroll
        for (int m = 0; m < 2; ++m) acc[a][m] = (f32x4){0.f, 0.f, 0.f, 0.f};
    sacc[0] = (f32x4){0.f, 0.f, 0.f, 0.f};
    sacc[1] = (f32x4){0.f, 0.f, 0.f, 0.f};

    const float* xr0 = X + (row0 + cr) * DIN;        // m=0 row
    const float* xr1 = X + (row0 + 16 + cr) * DIN;   // m=1 row

    for (int ks = 0; ks < 10; ++ks) {
        int k0 = ks * 32 + 8 * g;     // per-lane k base
        bf16x8 ahi[2], alo[2];
        #pragma unroll
        for (int m = 0; m < 2; ++m) {
            const float* xr = m ? xr1 : xr0;
            float x8[8];
            if (ks < 9) {
                f32x4 v0 = *(const f32x4*)(xr + k0);
                f32x4 v1 = *(const f32x4*)(xr + k0 + 4);
                #pragma unroll
                for (int j = 0; j < 4; ++j) { x8[j] = v0[j]; x8[4 + j] = v1[j]; }
            } else {
                #pragma unroll
                for (int j = 0; j < 8; ++j) {
                    int k = k0 + j;
                    x8[j] = (k < DIN) ? xr[k] : 0.f;
                }
            }
            #pragma unroll
            for (int j = 0; j < 8; ++j) {
                unsigned short h = f2bf(x8[j]);
                ahi[m][j] = (short)h;
                alo[m][j] = (short)f2bf(x8[j] - bf2f(h));
            }
        }
        #pragma unroll
        for (int ntl = 0; ntl < 5; ++ntl) {
            int c = (wv + 4 * ntl) * 16 + cr;
            bf16x8 bh = *(const bf16x8*)(W3T_hi + (size_t)c * 320 + k0);
            bf16x8 bl = *(const bf16x8*)(W3T_lo + (size_t)c * 320 + k0);
            #pragma unroll
            for (int m = 0; m < 2; ++m) {
                acc[ntl][m] = __builtin_amdgcn_mfma_f32_16x16x32_bf16(ahi[m], bh, acc[ntl][m], 0, 0, 0);
                acc[ntl][m] = __builtin_amdgcn_mfma_f32_16x16x32_bf16(ahi[m], bl, acc[ntl][m], 0, 0, 0);
                acc[ntl][m] = __builtin_amdgcn_mfma_f32_16x16x32_bf16(alo[m], bh, acc[ntl][m], 0, 0, 0);
            }
        }
        if (wv == 0) {
            bf16x8 uh = *(const bf16x8*)(UTh + ((size_t)n * 16 + cr) * 320 + k0);
            bf16x8 ul = *(const bf16x8*)(UTl + ((size_t)n * 16 + cr) * 320 + k0);
            #pragma unroll
            for (int m = 0; m < 2; ++m) {
                sacc[m] = __builtin_amdgcn_mfma_f32_16x16x32_bf16(ahi[m], uh, sacc[m], 0, 0, 0);
                sacc[m] = __builtin_amdgcn_mfma_f32_16x16x32_bf16(ahi[m], ul, sacc[m], 0, 0, 0);
                sacc[m] = __builtin_amdgcn_mfma_f32_16x16x32_bf16(alo[m], uh, sacc[m], 0, 0, 0);
            }
        }
    }

    // hm epilogue: mask, split, transposed store (q contiguous in j -> 8B)
    #pragma unroll
    for (int ntl = 0; ntl < 5; ++ntl) {
        int c = (wv + 4 * ntl) * 16 + cr;
        #pragma unroll
        for (int m = 0; m < 2; ++m) {
            u16x4 h4, l4;
            #pragma unroll
            for (int qq = 0; qq < 4; ++qq) {
                float v = acc[ntl][m][qq] * maskL[m * 16 + 4 * g + qq];
                unsigned short h = f2bf(v);
                h4[qq] = h;
                l4[qq] = f2bf(v - bf2f(h));
            }
            size_t off = ((size_t)(n * CPAD + c)) * Ee + j0 + m * 16 + 4 * g;
            *(u16x4*)(hmT_hi + off) = h4;
            *(u16x4*)(hmT_lo + off) = l4;
        }
    }

    // sdot epilogue: D[row][c], c=2i -> ssrc, c=2i+1 -> sdst
    if (wv == 0 && cr < 8) {
        int i = cr >> 1;
        float* dst = (cr & 1) ? sdst : ssrc;
        #pragma unroll
        for (int m = 0; m < 2; ++m)
            #pragma unroll
            for (int qq = 0; qq < 4; ++qq)
                dst[((size_t)i * Nn + n) * Ee + j0 + m * 16 + 4 * g + qq] = sacc[m][qq];
    }
}

// ---------------------------------------------------------------------------
// K5a: scores -> softmax -> A-fragment store. adj loaded as int4.
__global__ __launch_bounds__(256, 2) void score_kernel(
    const int*   __restrict__ adj,      // (N, E, E)
    const float* __restrict__ ssrc,     // (4, N, E)
    const float* __restrict__ sdst,     // (4, N, E)
    unsigned short* __restrict__ AH,    // (512 tiles, 16 ks, 2 m, 64 lane, 8)
    unsigned short* __restrict__ AL)
{
    int f  = blockIdx.x;
    int n  = (f & 7) * 4 + ((f >> 3) & 3);
    int rt = f >> 5;
    int tid = threadIdx.x;
    int row0 = rt * ROWS;

    __shared__ float coefT[Ee * 33];   // transposed coef [j][r], stride 33
    __shared__ float sdl[NT * Ee];
    __shared__ float ssl[NT * ROWS];

    for (int idx = tid; idx < NT * Ee; idx += 256) {
        int i = idx >> 9, j = idx & (Ee - 1);
        sdl[idx] = sdst[((size_t)i * Nn + n) * Ee + j];
    }
    for (int idx = tid; idx < NT * ROWS; idx += 256) {
        int i = idx >> 5, r = idx & 31;
        ssl[idx] = ssrc[((size_t)i * Nn + n) * Ee + row0 + r];
    }
    __syncthreads();

    const int* adjb = adj + ((size_t)n * Ee + row0) * Ee;
    for (int idx4 = tid; idx4 < (ROWS * Ee) / 4; idx4 += 256) {
        int r  = idx4 >> 7;
        int jb = (idx4 & 127) << 2;
        int4 t4 = *(const int4*)(adjb + (idx4 << 2));
        int tv[4] = {t4.x, t4.y, t4.z, t4.w};
        #pragma unroll
        for (int u = 0; u < 4; ++u) {
            int t = tv[u];
            int j = jb + u;
            float v;
            if (t > 0) {
                float x = ssl[(t - 1) * ROWS + r] + sdl[(t - 1) * Ee + j];
                v = (x >= 0.f) ? x : SLOPE * x;
            } else {
                v = -1e30f;
            }
            coefT[j * 33 + r] = v;
        }
    }
    __syncthreads();

    // softmax per row
    int wv = tid >> 6, lane = tid & 63;
    #pragma unroll
    for (int rr = 0; rr < 8; ++rr) {
        int r = wv * 8 + rr;
        float vals[8];
        float m = -3.0e38f;
        #pragma unroll
        for (int k = 0; k < 8; ++k) {
            vals[k] = coefT[(lane + 64 * k) * 33 + r];
            m = fmaxf(m, vals[k]);
        }
        #pragma unroll
        for (int off = 32; off; off >>= 1) m = fmaxf(m, __shfl_xor(m, off));
        float s = 0.f;
        #pragma unroll
        for (int k = 0; k < 8; ++k) {
            vals[k] = __expf(vals[k] - m);
            s += vals[k];
        }
        #pragma unroll
        for (int off = 32; off; off >>= 1) s += __shfl_xor(s, off);
        float inv = 1.f / s;
        #pragma unroll
        for (int k = 0; k < 8; ++k)
            coefT[(lane + 64 * k) * 33 + r] = vals[k] * inv;
    }
    __syncthreads();

    // A-fragment store: task t = ks*128 + m*64 + lane_; split inline.
    size_t tbase = ((size_t)(n * 16 + rt)) * 2048 * 8;
    for (int t = tid; t < 2048; t += 256) {
        int ks = t >> 7, rem = t & 127, m = rem >> 6, ln = rem & 63;
        int g2 = ln >> 4, cr2 = ln & 15;
        int k0 = ks * 32;
        bf16x8 hv, lv;
        #pragma unroll
        for (int jp = 0; jp < 8; ++jp) {
            float v = coefT[(k0 + 8 * g2 + jp) * 33 + m * 16 + cr2];
            unsigned short h = f2bf(v);
            hv[jp] = (short)h;
            lv[jp] = (short)f2bf(v - bf2f(h));
        }
        size_t o = tbase + (size_t)t * 8;
        *(bf16x8*)(AH + o) = hv;
        *(bf16x8*)(AL + o) = lv;
    }
}

// ---------------------------------------------------------------------------
// K5b: PV GEMM from pre-formatted fragments. No LDS, no barriers.
// grid (512, 5): x = (n, rt) tile via XCD decode, y = column group.
// Wave wv owns column tile ct = y*4+wv (one 16-col tile), 96 MFMAs/wave.
// 2560 blocks = 10 blocks/CU -> wave-slot saturated (was 2/CU, latency-bound).
__global__ __launch_bounds__(256) void pv_kernel(
    const unsigned short* __restrict__ AH,
    const unsigned short* __restrict__ AL,
    const unsigned short* __restrict__ hmT_hi,  // (32, CPAD, 512)
    const unsigned short* __restrict__ hmT_lo,
    float* __restrict__ out)            // (N, E, 300)
{
    int f  = blockIdx.x;
    int n  = (f & 7) * 4 + ((f >> 3) & 3);
    int rt = f >> 5;
    int tid = threadIdx.x, wv = tid >> 6, lane = tid & 63;
    int g = lane >> 4, cr = lane & 15;
    int row0 = rt * ROWS;
    int ct = blockIdx.y * 4 + wv;       // 0..19
    int c  = ct * 16 + cr;
    size_t tbase = ((size_t)(n * 16 + rt)) * 2048 * 8;
    const unsigned short* bh_base = hmT_hi + ((size_t)(n * CPAD + c)) * Ee;
    const unsigned short* bl_base = hmT_lo + ((size_t)(n * CPAD + c)) * Ee;

    f32x4 acc[2];
    acc[0] = (f32x4){0.f, 0.f, 0.f, 0.f};
    acc[1] = (f32x4){0.f, 0.f, 0.f, 0.f};

    for (int ks = 0; ks < 16; ++ks) {
        int k0 = ks * 32;
        bf16x8 bhi = *(const bf16x8*)(bh_base + k0 + 8 * g);
        bf16x8 blo = *(const bf16x8*)(bl_base + k0 + 8 * g);
        #pragma unroll
        for (int m = 0; m < 2; ++m) {
            size_t o = tbase + (size_t)((ks * 2 + m) * 64 + lane) * 8;
            bf16x8 ahi = *(const bf16x8*)(AH + o);
            bf16x8 alo = *(const bf16x8*)(AL + o);
            acc[m] = __builtin_amdgcn_mfma_f32_16x16x32_bf16(ahi, bhi, acc[m], 0, 0, 0);
            acc[m] = __builtin_amdgcn_mfma_f32_16x16x32_bf16(ahi, blo, acc[m], 0, 0, 0);
            acc[m] = __builtin_amdgcn_mfma_f32_16x16x32_bf16(alo, bhi, acc[m], 0, 0, 0);
        }
    }

    if (c < DOUT) {
        #pragma unroll
        for (int m = 0; m < 2; ++m) {
            #pragma unroll
            for (int q = 0; q < 4; ++q) {
                int erow = row0 + m * 16 + 4 * g + q;
                out[((size_t)n * Ee + erow) * DOUT + c] = acc[m][q];
            }
        }
    }
}

// ---------------------------------------------------------------------------
// Fallback-path kernels (only if ws too small for split; never expected).
__global__ __launch_bounds__(256) void gates1_kernel(
    const float* __restrict__ q, const float* __restrict__ W1,
    float* __restrict__ t1)
{
    int i = blockIdx.y;
    int idx = blockIdx.x * 256 + threadIdx.x;
    int n = idx / 600, j = idx - n * 600;
    const float* W1i = W1 + (size_t)i * QD * 600;
    const float* qn = q + n * QD;
    float a0 = 0.f, a1 = 0.f;
    #pragma unroll 5
    for (int k = 0; k < QD; k += 2) {
        a0 += qn[k]     * W1i[(size_t)k * 600 + j];
        a1 += qn[k + 1] * W1i[(size_t)(k + 1) * 600 + j];
    }
    t1[((size_t)i * Nn + n) * 600 + j] = fmaxf(a0 + a1, 0.f);
}

__global__ __launch_bounds__(256) void gates2_kernel(
    const float* __restrict__ t1, const float* __restrict__ W2,
    float* __restrict__ g)
{
    int i = blockIdx.y;
    int idx = blockIdx.x * 256 + threadIdx.x;
    int n = idx / 600, j = idx - n * 600;
    const float* W2i = W2 + (size_t)i * 600 * 600;
    const float* tn = t1 + ((size_t)i * Nn + n) * 600;
    float a0 = 0.f, a1 = 0.f;
    #pragma unroll 5
    for (int k = 0; k < 600; k += 2) {
        a0 += tn[k]     * W2i[(size_t)k * 600 + j];
        a1 += tn[k + 1] * W2i[(size_t)(k + 1) * 600 + j];
    }
    g[((size_t)i * Nn + n) * 600 + j] = 1.f / (1.f + __expf(-(a0 + a1)));
}

__global__ __launch_bounds__(64) void uvec_kernel(
    const float* __restrict__ W, const float* __restrict__ a,
    const float* __restrict__ g,
    unsigned short* __restrict__ UTh, unsigned short* __restrict__ UTl)
{
    int i = blockIdx.x, n = blockIdx.y, kt = blockIdx.z;
    int lane = threadIdx.x;
    __shared__ float w1[DOUT], w2[DOUT];

    const float* gi = g + ((size_t)i * Nn + n) * 600;
    const float* ai = a + (size_t)i * 600;
    for (int d = lane; d < DOUT; d += 64) {
        w1[d] = gi[d] * ai[d];
        w2[d] = gi[DOUT + d] * ai[DOUT + d];
    }
    __syncthreads();

    int k0 = kt * 38;
    int k1 = k0 + 38 < DIN ? k0 + 38 : DIN;
    const float* Wi = W + (size_t)i * DIN * DOUT;
    for (int k = k0; k < k1; ++k) {
        const float* Wk = Wi + (size_t)k * DOUT;
        float s1 = 0.f, s2 = 0.f;
        #pragma unroll
        for (int c = 0; c < 5; ++c) {
            int d = lane + 64 * c;
            if (d < DOUT) { float w = Wk[d]; s1 += w * w1[d]; s2 += w * w2[d]; }
        }
        #pragma unroll
        for (int off = 32; off; off >>= 1) {
            s1 += __shfl_xor(s1, off);
            s2 += __shfl_xor(s2, off);
        }
        if (lane == 0) {
            unsigned short h1 = f2bf(s1), l1 = f2bf(s1 - bf2f(h1));
            unsigned short h2 = f2bf(s2), l2 = f2bf(s2 - bf2f(h2));
            size_t b = ((size_t)n * 16 + 2 * i) * 320 + k;
            UTh[b] = h1;       UTl[b] = l1;
            UTh[b + 320] = h2; UTl[b + 320] = l2;
        }
    }
}

__global__ __launch_bounds__(256, 2) void attn_kernel(
    const int*   __restrict__ adj,
    const float* __restrict__ ssrc,
    const float* __restrict__ sdst,
    const unsigned short* __restrict__ hmT_hi,
    const unsigned short* __restrict__ hmT_lo,
    float* __restrict__ out)
{
    int f  = blockIdx.x;
    int n  = (f & 7) * 4 + ((f >> 3) & 3);
    int rt = f >> 5;
    int tid = threadIdx.x;
    int row0 = rt * ROWS;

    __shared__ unsigned coefT[Ee * 33];
    __shared__ float sdl[NT * Ee];
    __shared__ float ssl[NT * ROWS];

    for (int idx = tid; idx < NT * Ee; idx += 256) {
        int i = idx >> 9, j = idx & (Ee - 1);
        sdl[idx] = sdst[((size_t)i * Nn + n) * Ee + j];
    }
    for (int idx = tid; idx < NT * ROWS; idx += 256) {
        int i = idx >> 5, r = idx & 31;
        ssl[idx] = ssrc[((size_t)i * Nn + n) * Ee + row0 + r];
    }
    __syncthreads();

    const int* adjb = adj + ((size_t)n * Ee + row0) * Ee;
    for (int idx = tid; idx < ROWS * Ee; idx += 256) {
        int r = idx >> 9, j = idx & (Ee - 1);
        int t = adjb[idx];
        float v;
        if (t > 0) {
            float x = ssl[(t - 1) * ROWS + r] + sdl[(t - 1) * Ee + j];
            v = (x >= 0.f) ? x : SLOPE * x;
        } else {
            v = -1e30f;
        }
        coefT[j * 33 + r] = __float_as_uint(v);
    }
    __syncthreads();

    int wv = tid >> 6, lane = tid & 63;
    #pragma unroll
    for (int rr = 0; rr < 8; ++rr) {
        int r = wv * 8 + rr;
        float vals[8];
        float m = -3.0e38f;
        #pragma unroll
        for (int k = 0; k < 8; ++k) {
            vals[k] = __uint_as_float(coefT[(lane + 64 * k) * 33 + r]);
            m = fmaxf(m, vals[k]);
        }
        #pragma unroll
        for (int off = 32; off; off >>= 1) m = fmaxf(m, __shfl_xor(m, off));
        float s = 0.f;
        #pragma unroll
        for (int k = 0; k < 8; ++k) {
            vals[k] = __expf(vals[k] - m);
            s += vals[k];
        }
        #pragma unroll
        for (int off = 32; off; off >>= 1) s += __shfl_xor(s, off);
        float inv = 1.f / s;
        #pragma unroll
        for (int k = 0; k < 8; ++k)
            coefT[(lane + 64 * k) * 33 + r] = __float_as_uint(vals[k] * inv);
    }
    __syncthreads();

    for (int idx = tid; idx < Ee * ROWS; idx += 256) {
        int j = idx >> 5, r = idx & 31;
        float v = __uint_as_float(coefT[j * 33 + r]);
        unsigned short hi = f2bf(v);
        unsigned short lo = f2bf(v - bf2f(hi));
        coefT[j * 33 + r] = ((unsigned)hi << 16) | (unsigned)lo;
    }
    __syncthreads();

    int g = lane >> 4;
    int cr = lane & 15;
    f32x4 acc[5][2];
    #pragma unroll
    for (int a = 0; a < 5; ++a)
        #pragma unroll
        for (int m = 0; m < 2; ++m) acc[a][m] = (f32x4){0.f, 0.f, 0.f, 0.f};

    for (int ks = 0; ks < 16; ++ks) {
        int k0 = ks * 32;
        bf16x8 ahi[2], alo[2];
        #pragma unroll
        for (int m = 0; m < 2; ++m) {
            #pragma unroll
            for (int j = 0; j < 8; ++j) {
                unsigned v = coefT[(k0 + 8 * g + j) * 33 + m * 16 + cr];
                ahi[m][j] = (short)(v >> 16);
                alo[m][j] = (short)(v & 0xffffu);
            }
        }
        #pragma unroll
        for (int ntl = 0; ntl < 5; ++ntl) {
            int c = (wv + 4 * ntl) * 16 + cr;
            size_t off = ((size_t)(n * CPAD + c)) * Ee + k0 + 8 * g;
            bf16x8 bhi = *(const bf16x8*)(hmT_hi + off);
            bf16x8 blo = *(const bf16x8*)(hmT_lo + off);
            #pragma unroll
            for (int m = 0; m < 2; ++m) {
                acc[ntl][m] = __builtin_amdgcn_mfma_f32_16x16x32_bf16(ahi[m], bhi, acc[ntl][m], 0, 0, 0);
                acc[ntl][m] = __builtin_amdgcn_mfma_f32_16x16x32_bf16(ahi[m], blo, acc[ntl][m], 0, 0, 0);
                acc[ntl][m] = __builtin_amdgcn_mfma_f32_16x16x32_bf16(alo[m], bhi, acc[ntl][m], 0, 0, 0);
            }
        }
    }

    #pragma unroll
    for (int ntl = 0; ntl < 5; ++ntl) {
        int c = (wv + 4 * ntl) * 16 + cr;
        if (c < DOUT) {
            #pragma unroll
            for (int m = 0; m < 2; ++m) {
                #pragma unroll
                for (int q = 0; q < 4; ++q) {
                    int erow = row0 + m * 16 + 4 * g + q;
                    out[((size_t)n * Ee + erow) * DOUT + c] = acc[ntl][m][q];
                }
            }
        }
    }
}

// ---------------------------------------------------------------------------
extern "C" void kernel_launch(void* const* d_in, const int* in_sizes, int n_in,
                              void* d_out, int out_size, void* d_ws, size_t ws_size,
                              hipStream_t stream) {
    const float* input_state = (const float*)d_in[0];
    const int*   adj         = (const int*)  d_in[1];
    const float* node_mask   = (const float*)d_in[2];
    const float* query_vec   = (const float*)d_in[3];
    const float* W_type      = (const float*)d_in[4];
    const float* a_type      = (const float*)d_in[5];
    const float* qattn_W1    = (const float*)d_in[6];
    const float* qattn_W2    = (const float*)d_in[7];
    float* out = (float*)d_out;

    // workspace layout (same footprint as round 4-8; split path verified used)
    float* ws   = (float*)d_ws;
    float* g    = ws;                 // 76800 f (fallback path only)
    float* t1   = g    + 76800;       // 76800 f
    float* ssrc = t1   + 76800;       // 65536 f
    float* sdst = ssrc + 65536;       // 65536 f
    unsigned short* W3T_hi = (unsigned short*)(sdst + 65536);   // 102400 u16
    unsigned short* W3T_lo = W3T_hi + 320 * 320;                // 102400 u16
    unsigned short* GTh    = W3T_lo + 320 * 320;                // 81920 u16
    unsigned short* GTl    = GTh + 4 * 64 * 320;                // 81920 u16
    unsigned short* UTh    = GTl + 4 * 64 * 320;                // 163840 u16
    unsigned short* UTl    = UTh + 32 * 16 * 320;               // 163840 u16
    unsigned short* hmT_hi = UTl + 32 * 16 * 320;               // 5242880 u16
    unsigned short* hmT_lo = hmT_hi + (size_t)Nn * CPAD * Ee;   // 5242880 u16
    unsigned short* AH     = hmT_lo + (size_t)Nn * CPAD * Ee;   // 8388608 u16
    unsigned short* AL     = AH + (size_t)512 * 2048 * 8;       // 8388608 u16
    // gates partial buffers alias AH region (dead until score_kernel)
    float* t1p = (float*)AH;          // 307200 f
    float* gp  = t1p + 307200;        // 307200 f

    size_t need_split = (size_t)((char*)(AL + (size_t)512 * 2048 * 8) - (char*)d_ws);
    bool use_split = ws_size >= need_split;

    hipLaunchKernelGGL(prep_kernel, dim3(640), dim3(256), 0, stream,
                       W_type + 3 * DIN * DOUT, W3T_hi, W3T_lo, UTh, UTl, GTh, GTl);
    if (use_split) {
        hipLaunchKernelGGL(gates1_part_kernel, dim3(75, NT, 4), dim3(256), 0, stream,
                           query_vec, qattn_W1, t1p);
        hipLaunchKernelGGL(gates1_fin_kernel, dim3(75, NT), dim3(256), 0, stream,
                           t1p, t1);
        hipLaunchKernelGGL(gates2_part_kernel, dim3(75, NT, 4), dim3(256), 0, stream,
                           t1, qattn_W2, gp);
        hipLaunchKernelGGL(gates2_fin_kernel, dim3(75, NT), dim3(256), 0, stream,
                           gp, a_type, GTh, GTl);
        hipLaunchKernelGGL(uvec_mfma_kernel, dim3(5, NT), dim3(256), 0, stream,
                           W_type, GTh, GTl, UTh, UTl);
        hipLaunchKernelGGL(hm_mfma_kernel, dim3((Nn * Ee) / 32), dim3(256), 0, stream,
                           input_state, node_mask, W3T_hi, W3T_lo, UTh, UTl,
                           hmT_hi, hmT_lo, ssrc, sdst);
        hipLaunchKernelGGL(score_kernel, dim3(512), dim3(256), 0, stream,
                           adj, ssrc, sdst, AH, AL);
        hipLaunchKernelGGL(pv_kernel, dim3(512, 5), dim3(256), 0, stream,
                           AH, AL, hmT_hi, hmT_lo, out);
    } else {
        hipLaunchKernelGGL(gates1_kernel, dim3(75, NT), dim3(256), 0, stream,
                           query_vec, qattn_W1, t1);
        hipLaunchKernelGGL(gates2_kernel, dim3(75, NT), dim3(256), 0, stream,
                           t1, qattn_W2, g);
        hipLaunchKernelGGL(uvec_kernel, dim3(NT, Nn, 8), dim3(64), 0, stream,
                           W_type, a_type, g, UTh, UTl);
        hipLaunchKernelGGL(hm_mfma_kernel, dim3((Nn * Ee) / 32), dim3(256), 0, stream,
                           input_state, node_mask, W3T_hi, W3T_lo, UTh, UTl,
                           hmT_hi, hmT_lo, ssrc, sdst);
        hipLaunchKernelGGL(attn_kernel, dim3(512), dim3(256), 0, stream,
                           adj, ssrc, sdst, hmT_hi, hmT_lo, out);
    }
}

// Round 11
// 142.350 us; speedup vs baseline: 1.2377x; 1.2377x over previous
//
#include <hip/hip_runtime.h>
#include <hip/hip_bf16.h>

// Problem constants
#define Nn   32
#define Ee   512
#define DIN  300
#define DOUT 300
#define NT   4
#define QD   300
#define SLOPE 0.2f
#define ROWS 32   // rows per tile in attn kernel
#define CPAD 320  // padded d-dim for hmT (20 MFMA n-tiles of 16)

typedef __attribute__((ext_vector_type(8))) short bf16x8;
typedef __attribute__((ext_vector_type(4))) float f32x4;
typedef __attribute__((ext_vector_type(4))) unsigned short u16x4;

__device__ inline unsigned short f2bf(float x) {
    __hip_bfloat16 h = __float2bfloat16(x);   // RNE
    return *reinterpret_cast<unsigned short*>(&h);
}
__device__ inline float bf2f(unsigned short u) {
    __hip_bfloat16 h = *reinterpret_cast<__hip_bfloat16*>(&u);
    return __bfloat162float(h);
}

// ---------------------------------------------------------------------------
// K0: prep. W3T split planes [c=320][k=320] (W3T[c][k] = W3[k][c], pad 0),
// zero UT planes [32][16][320], zero GT planes [4][64][320].
__global__ __launch_bounds__(256) void prep_kernel(
    const float* __restrict__ W3,          // (300, 300)  row k, col d
    unsigned short* __restrict__ W3T_hi,   // (320, 320)
    unsigned short* __restrict__ W3T_lo,
    unsigned short* __restrict__ UTh,      // (32, 16, 320)
    unsigned short* __restrict__ UTl,
    unsigned short* __restrict__ GTh,      // (4, 64, 320)
    unsigned short* __restrict__ GTl)
{
    int idx = blockIdx.x * 256 + threadIdx.x;   // grid 640 -> 163840 threads
    if (idx < 320 * 320) {
        int c = idx / 320, k = idx - c * 320;
        float v = (c < DOUT && k < DIN) ? W3[(size_t)k * DOUT + c] : 0.f;
        unsigned short h = f2bf(v);
        W3T_hi[idx] = h;
        W3T_lo[idx] = f2bf(v - bf2f(h));
    }
    if (idx < 32 * 16 * 320) { UTh[idx] = 0; UTl[idx] = 0; }
    if (idx < 4 * 64 * 320)  { GTh[idx] = 0; GTl[idx] = 0; }
}

// ---------------------------------------------------------------------------
// K1a: gates1 partial. t1p[z][i][n][j] = sum_{k in slab z} q[n][k]*W1[i][k][j]
// grid (75, NT, 4), block 256.
__global__ __launch_bounds__(256) void gates1_part_kernel(
    const float* __restrict__ q,    // (32, 300)
    const float* __restrict__ W1,   // (4, 300, 600)
    float* __restrict__ t1p)        // (4, 4, 32, 600)
{
    int i = blockIdx.y, z = blockIdx.z;
    int idx = blockIdx.x * 256 + threadIdx.x;   // 0..19199
    int n = idx / 600, j = idx - n * 600;
    const float* W1i = W1 + (size_t)i * QD * 600;
    const float* qn = q + n * QD;
    int k0 = z * 75;
    float a0 = 0.f;
    #pragma unroll 5
    for (int k = k0; k < k0 + 75; ++k)
        a0 += qn[k] * W1i[(size_t)k * 600 + j];
    t1p[((size_t)(z * NT + i) * Nn + n) * 600 + j] = a0;
}

// K1a-fin: t1 = relu(sum_z t1p). grid (75, NT).
__global__ __launch_bounds__(256) void gates1_fin_kernel(
    const float* __restrict__ t1p, float* __restrict__ t1)
{
    int i = blockIdx.y;
    int idx = blockIdx.x * 256 + threadIdx.x;
    size_t o = ((size_t)i * Nn) * 600 + idx;
    float s = t1p[o] + t1p[o + 76800] + t1p[o + 2 * 76800] + t1p[o + 3 * 76800];
    t1[o] = fmaxf(s, 0.f);
}

// ---------------------------------------------------------------------------
// K1b: gates2 partial. K=600, 4 slabs of 150.
__global__ __launch_bounds__(256) void gates2_part_kernel(
    const float* __restrict__ t1,   // (4, 32, 600)
    const float* __restrict__ W2,   // (4, 600, 600)
    float* __restrict__ gp)         // (4, 4, 32, 600)
{
    int i = blockIdx.y, z = blockIdx.z;
    int idx = blockIdx.x * 256 + threadIdx.x;
    int n = idx / 600, j = idx - n * 600;
    const float* W2i = W2 + (size_t)i * 600 * 600;
    const float* tn = t1 + ((size_t)i * Nn + n) * 600;
    int k0 = z * 150;
    float a0 = 0.f, a1 = 0.f;
    #pragma unroll 5
    for (int k = k0; k < k0 + 150; k += 2) {
        a0 += tn[k]     * W2i[(size_t)k * 600 + j];
        a1 += tn[k + 1] * W2i[(size_t)(k + 1) * 600 + j];
    }
    gp[((size_t)(z * NT + i) * Nn + n) * 600 + j] = a0 + a1;
}

// K1b-fin: gate = sigmoid(sum_z gp) * a  -> GT split planes [i][2n+s][d].
// grid (75, NT).
__global__ __launch_bounds__(256) void gates2_fin_kernel(
    const float* __restrict__ gp,
    const float* __restrict__ a,    // (4, 600)
    unsigned short* __restrict__ GTh,   // (4, 64, 320)
    unsigned short* __restrict__ GTl)
{
    int i = blockIdx.y;
    int idx = blockIdx.x * 256 + threadIdx.x;
    int n = idx / 600, j = idx - n * 600;
    size_t o = ((size_t)i * Nn + n) * 600 + j;
    float s = gp[o] + gp[o + 76800] + gp[o + 2 * 76800] + gp[o + 3 * 76800];
    float w = (1.f / (1.f + __expf(-s))) * a[(size_t)i * 600 + j];
    int s2 = (j >= DOUT) ? 1 : 0;
    int d = j - s2 * DOUT;
    int c = 2 * n + s2;
    size_t go = ((size_t)i * 64 + c) * 320 + d;
    unsigned short h = f2bf(w);
    GTh[go] = h;
    GTl[go] = f2bf(w - bf2f(h));
}

// ---------------------------------------------------------------------------
// K2: uvec via MFMA. Per type i: U = W[i](300k x 300d) @ GT[i]^T(300d x 64c).
// grid (5, NT), block 256 (4 waves).
__global__ __launch_bounds__(256) void uvec_mfma_kernel(
    const float* __restrict__ W,            // (4, 300, 300)
    const unsigned short* __restrict__ GTh, // (4, 64, 320)
    const unsigned short* __restrict__ GTl,
    unsigned short* __restrict__ UTh,       // (32, 16, 320)
    unsigned short* __restrict__ UTl)
{
    int mc = blockIdx.x, i = blockIdx.y;
    int tid = threadIdx.x, wv = tid >> 6, lane = tid & 63;
    int g = lane >> 4, cr = lane & 15;
    int m0 = mc * 64 + wv * 16;
    int arow = m0 + cr;
    const float* wr = W + (size_t)i * DIN * DOUT
                        + (size_t)(arow < DIN ? arow : 0) * DOUT;

    f32x4 acc[4];
    #pragma unroll
    for (int nt = 0; nt < 4; ++nt) acc[nt] = (f32x4){0.f, 0.f, 0.f, 0.f};

    for (int ks = 0; ks < 10; ++ks) {
        int k0 = ks * 32 + 8 * g;
        float x8[8];
        if (ks < 9) {
            f32x4 v0 = *(const f32x4*)(wr + k0);
            f32x4 v1 = *(const f32x4*)(wr + k0 + 4);
            #pragma unroll
            for (int j = 0; j < 4; ++j) { x8[j] = v0[j]; x8[4 + j] = v1[j]; }
        } else {
            #pragma unroll
            for (int j = 0; j < 8; ++j) {
                int d = k0 + j;
                x8[j] = (d < DOUT) ? wr[d] : 0.f;
            }
        }
        bf16x8 ahi, alo;
        #pragma unroll
        for (int j = 0; j < 8; ++j) {
            unsigned short h = f2bf(x8[j]);
            ahi[j] = (short)h;
            alo[j] = (short)f2bf(x8[j] - bf2f(h));
        }
        #pragma unroll
        for (int nt = 0; nt < 4; ++nt) {
            size_t bo = ((size_t)i * 64 + nt * 16 + cr) * 320 + k0;
            bf16x8 bh = *(const bf16x8*)(GTh + bo);
            bf16x8 bl = *(const bf16x8*)(GTl + bo);
            acc[nt] = __builtin_amdgcn_mfma_f32_16x16x32_bf16(ahi, bh, acc[nt], 0, 0, 0);
            acc[nt] = __builtin_amdgcn_mfma_f32_16x16x32_bf16(ahi, bl, acc[nt], 0, 0, 0);
            acc[nt] = __builtin_amdgcn_mfma_f32_16x16x32_bf16(alo, bh, acc[nt], 0, 0, 0);
        }
    }

    int krow = m0 + 4 * g;   // 4-aligned; 300%4==0 so group fully in or out
    if (krow < DIN) {
        #pragma unroll
        for (int nt = 0; nt < 4; ++nt) {
            int c = nt * 16 + cr;
            int n = c >> 1, s = c & 1;
            size_t base = ((size_t)n * 16 + 2 * i + s) * 320 + krow;
            u16x4 h4, l4;
            #pragma unroll
            for (int q = 0; q < 4; ++q) {
                float v = acc[nt][q];
                unsigned short h = f2bf(v);
                h4[q] = h;
                l4[q] = f2bf(v - bf2f(h));
            }
            *(u16x4*)(UTh + base) = h4;
            *(u16x4*)(UTl + base) = l4;
        }
    }
}

// ---------------------------------------------------------------------------
// K4: MFMA hm GEMM + fused sdot (unchanged).
__global__ __launch_bounds__(256) void hm_mfma_kernel(
    const float* __restrict__ X,               // (16384, 300)
    const float* __restrict__ mask,            // (16384)
    const unsigned short* __restrict__ W3T_hi, // (320, 320)
    const unsigned short* __restrict__ W3T_lo,
    const unsigned short* __restrict__ UTh,    // (32, 16, 320)
    const unsigned short* __restrict__ UTl,
    unsigned short* __restrict__ hmT_hi,       // (32, CPAD, 512)
    unsigned short* __restrict__ hmT_lo,
    float* __restrict__ ssrc,                  // (4, 32, 512)
    float* __restrict__ sdst)
{
    int tid = threadIdx.x, wv = tid >> 6, lane = tid & 63;
    int g = lane >> 4, cr = lane & 15;
    size_t row0 = (size_t)blockIdx.x * 32;
    int n = (int)(row0 >> 9), j0 = (int)(row0 & 511);

    __shared__ float maskL[32];
    if (tid < 32) maskL[tid] = mask[row0 + tid];
    __syncthreads();

    f32x4 acc[5][2];
    f32x4 sacc[2];
    #pragma unroll
    for (int a = 0; a < 5; ++a)
        #pragma unroll
        for (int m = 0; m < 2; ++m) acc[a][m] = (f32x4){0.f, 0.f, 0.f, 0.f};
    sacc[0] = (f32x4){0.f, 0.f, 0.f, 0.f};
    sacc[1] = (f32x4){0.f, 0.f, 0.f, 0.f};

    const float* xr0 = X + (row0 + cr) * DIN;        // m=0 row
    const float* xr1 = X + (row0 + 16 + cr) * DIN;   // m=1 row

    for (int ks = 0; ks < 10; ++ks) {
        int k0 = ks * 32 + 8 * g;     // per-lane k base
        bf16x8 ahi[2], alo[2];
        #pragma unroll
        for (int m = 0; m < 2; ++m) {
            const float* xr = m ? xr1 : xr0;
            float x8[8];
            if (ks < 9) {
                f32x4 v0 = *(const f32x4*)(xr + k0);
                f32x4 v1 = *(const f32x4*)(xr + k0 + 4);
                #pragma unroll
                for (int j = 0; j < 4; ++j) { x8[j] = v0[j]; x8[4 + j] = v1[j]; }
            } else {
                #pragma unroll
                for (int j = 0; j < 8; ++j) {
                    int k = k0 + j;
                    x8[j] = (k < DIN) ? xr[k] : 0.f;
                }
            }
            #pragma unroll
            for (int j = 0; j < 8; ++j) {
                unsigned short h = f2bf(x8[j]);
                ahi[m][j] = (short)h;
                alo[m][j] = (short)f2bf(x8[j] - bf2f(h));
            }
        }
        #pragma unroll
        for (int ntl = 0; ntl < 5; ++ntl) {
            int c = (wv + 4 * ntl) * 16 + cr;
            bf16x8 bh = *(const bf16x8*)(W3T_hi + (size_t)c * 320 + k0);
            bf16x8 bl = *(const bf16x8*)(W3T_lo + (size_t)c * 320 + k0);
            #pragma unroll
            for (int m = 0; m < 2; ++m) {
                acc[ntl][m] = __builtin_amdgcn_mfma_f32_16x16x32_bf16(ahi[m], bh, acc[ntl][m], 0, 0, 0);
                acc[ntl][m] = __builtin_amdgcn_mfma_f32_16x16x32_bf16(ahi[m], bl, acc[ntl][m], 0, 0, 0);
                acc[ntl][m] = __builtin_amdgcn_mfma_f32_16x16x32_bf16(alo[m], bh, acc[ntl][m], 0, 0, 0);
            }
        }
        if (wv == 0) {
            bf16x8 uh = *(const bf16x8*)(UTh + ((size_t)n * 16 + cr) * 320 + k0);
            bf16x8 ul = *(const bf16x8*)(UTl + ((size_t)n * 16 + cr) * 320 + k0);
            #pragma unroll
            for (int m = 0; m < 2; ++m) {
                sacc[m] = __builtin_amdgcn_mfma_f32_16x16x32_bf16(ahi[m], uh, sacc[m], 0, 0, 0);
                sacc[m] = __builtin_amdgcn_mfma_f32_16x16x32_bf16(ahi[m], ul, sacc[m], 0, 0, 0);
                sacc[m] = __builtin_amdgcn_mfma_f32_16x16x32_bf16(alo[m], uh, sacc[m], 0, 0, 0);
            }
        }
    }

    // hm epilogue: mask, split, transposed store (q contiguous in j -> 8B)
    #pragma unroll
    for (int ntl = 0; ntl < 5; ++ntl) {
        int c = (wv + 4 * ntl) * 16 + cr;
        #pragma unroll
        for (int m = 0; m < 2; ++m) {
            u16x4 h4, l4;
            #pragma unroll
            for (int qq = 0; qq < 4; ++qq) {
                float v = acc[ntl][m][qq] * maskL[m * 16 + 4 * g + qq];
                unsigned short h = f2bf(v);
                h4[qq] = h;
                l4[qq] = f2bf(v - bf2f(h));
            }
            size_t off = ((size_t)(n * CPAD + c)) * Ee + j0 + m * 16 + 4 * g;
            *(u16x4*)(hmT_hi + off) = h4;
            *(u16x4*)(hmT_lo + off) = l4;
        }
    }

    // sdot epilogue: D[row][c], c=2i -> ssrc, c=2i+1 -> sdst
    if (wv == 0 && cr < 8) {
        int i = cr >> 1;
        float* dst = (cr & 1) ? sdst : ssrc;
        #pragma unroll
        for (int m = 0; m < 2; ++m)
            #pragma unroll
            for (int qq = 0; qq < 4; ++qq)
                dst[((size_t)i * Nn + n) * Ee + j0 + m * 16 + 4 * g + qq] = sacc[m][qq];
    }
}

// ---------------------------------------------------------------------------
// K5: FUSED scores -> softmax -> pack -> PV. 8 waves (512 threads), grid 512.
// A-fragments stay in LDS (coefT) -> no 67MB AH/AL round-trip, low-latency
// A reads. 76KB LDS -> 2 blocks/CU -> 16 waves/CU (2x the 4-wave version).
// Wave wv: softmax rows wv*4..+3; PV col-tiles {wv, wv+8, wv+16} (<20).
__global__ __launch_bounds__(512, 4) void attn8_kernel(
    const int*   __restrict__ adj,      // (N, E, E)
    const float* __restrict__ ssrc,     // (4, N, E)
    const float* __restrict__ sdst,     // (4, N, E)
    const unsigned short* __restrict__ hmT_hi,  // (32, CPAD, 512)
    const unsigned short* __restrict__ hmT_lo,
    float* __restrict__ out)            // (N, E, 300)
{
    int f  = blockIdx.x;
    int n  = (f & 7) * 4 + ((f >> 3) & 3);   // XCD-local n
    int rt = f >> 5;
    int tid = threadIdx.x;
    int row0 = rt * ROWS;

    __shared__ unsigned coefT[Ee * 33];   // [j][r] stride 33, 67.5 KB
    __shared__ float sdl[NT * Ee];
    __shared__ float ssl[NT * ROWS];

    for (int idx = tid; idx < NT * Ee; idx += 512) {
        int i = idx >> 9, j = idx & (Ee - 1);
        sdl[idx] = sdst[((size_t)i * Nn + n) * Ee + j];
    }
    for (int idx = tid; idx < NT * ROWS; idx += 512) {
        int i = idx >> 5, r = idx & 31;
        ssl[idx] = ssrc[((size_t)i * Nn + n) * Ee + row0 + r];
    }
    __syncthreads();

    // scores (adj as int4, write transposed)
    const int* adjb = adj + ((size_t)n * Ee + row0) * Ee;
    for (int idx4 = tid; idx4 < (ROWS * Ee) / 4; idx4 += 512) {
        int r  = idx4 >> 7;
        int jb = (idx4 & 127) << 2;
        int4 t4 = *(const int4*)(adjb + (idx4 << 2));
        int tv[4] = {t4.x, t4.y, t4.z, t4.w};
        #pragma unroll
        for (int u = 0; u < 4; ++u) {
            int t = tv[u];
            int j = jb + u;
            float v;
            if (t > 0) {
                float x = ssl[(t - 1) * ROWS + r] + sdl[(t - 1) * Ee + j];
                v = (x >= 0.f) ? x : SLOPE * x;
            } else {
                v = -1e30f;
            }
            coefT[j * 33 + r] = __float_as_uint(v);
        }
    }
    __syncthreads();

    // softmax: wave wv owns rows wv*4..wv*4+3
    int wv = tid >> 6, lane = tid & 63;
    #pragma unroll
    for (int rr = 0; rr < 4; ++rr) {
        int r = wv * 4 + rr;
        float vals[8];
        float m = -3.0e38f;
        #pragma unroll
        for (int k = 0; k < 8; ++k) {
            vals[k] = __uint_as_float(coefT[(lane + 64 * k) * 33 + r]);
            m = fmaxf(m, vals[k]);
        }
        #pragma unroll
        for (int off = 32; off; off >>= 1) m = fmaxf(m, __shfl_xor(m, off));
        float s = 0.f;
        #pragma unroll
        for (int k = 0; k < 8; ++k) {
            vals[k] = __expf(vals[k] - m);
            s += vals[k];
        }
        #pragma unroll
        for (int off = 32; off; off >>= 1) s += __shfl_xor(s, off);
        float inv = 1.f / s;
        #pragma unroll
        for (int k = 0; k < 8; ++k)
            coefT[(lane + 64 * k) * 33 + r] = __float_as_uint(vals[k] * inv);
    }
    __syncthreads();

    // pack coef -> (bf16_hi << 16) | bf16_lo, in place
    for (int idx = tid; idx < Ee * ROWS; idx += 512) {
        int j = idx >> 5, r = idx & 31;
        float v = __uint_as_float(coefT[j * 33 + r]);
        unsigned short hi = f2bf(v);
        unsigned short lo = f2bf(v - bf2f(hi));
        coefT[j * 33 + r] = ((unsigned)hi << 16) | (unsigned)lo;
    }
    __syncthreads();

    // PV: wave wv owns col-tiles {wv, wv+8, wv+16} ∩ [0,20)
    int g = lane >> 4, cr = lane & 15;
    f32x4 acc[3][2];
    #pragma unroll
    for (int t = 0; t < 3; ++t)
        #pragma unroll
        for (int m = 0; m < 2; ++m) acc[t][m] = (f32x4){0.f, 0.f, 0.f, 0.f};

    for (int ks = 0; ks < 16; ++ks) {
        int k0 = ks * 32;
        bf16x8 ahi[2], alo[2];
        #pragma unroll
        for (int m = 0; m < 2; ++m) {
            #pragma unroll
            for (int j = 0; j < 8; ++j) {
                unsigned v = coefT[(k0 + 8 * g + j) * 33 + m * 16 + cr];
                ahi[m][j] = (short)(v >> 16);
                alo[m][j] = (short)(v & 0xffffu);
            }
        }
        #pragma unroll
        for (int t = 0; t < 3; ++t) {
            int ct = wv + 8 * t;
            if (ct < 20) {
                int c = ct * 16 + cr;
                size_t off = ((size_t)(n * CPAD + c)) * Ee + k0 + 8 * g;
                bf16x8 bhi = *(const bf16x8*)(hmT_hi + off);
                bf16x8 blo = *(const bf16x8*)(hmT_lo + off);
                #pragma unroll
                for (int m = 0; m < 2; ++m) {
                    acc[t][m] = __builtin_amdgcn_mfma_f32_16x16x32_bf16(ahi[m], bhi, acc[t][m], 0, 0, 0);
                    acc[t][m] = __builtin_amdgcn_mfma_f32_16x16x32_bf16(ahi[m], blo, acc[t][m], 0, 0, 0);
                    acc[t][m] = __builtin_amdgcn_mfma_f32_16x16x32_bf16(alo[m], bhi, acc[t][m], 0, 0, 0);
                }
            }
        }
    }

    #pragma unroll
    for (int t = 0; t < 3; ++t) {
        int ct = wv + 8 * t;
        if (ct < 20) {
            int c = ct * 16 + cr;
            if (c < DOUT) {
                #pragma unroll
                for (int m = 0; m < 2; ++m) {
                    #pragma unroll
                    for (int q = 0; q < 4; ++q) {
                        int erow = row0 + m * 16 + 4 * g + q;
                        out[((size_t)n * Ee + erow) * DOUT + c] = acc[t][m][q];
                    }
                }
            }
        }
    }
}

// ---------------------------------------------------------------------------
extern "C" void kernel_launch(void* const* d_in, const int* in_sizes, int n_in,
                              void* d_out, int out_size, void* d_ws, size_t ws_size,
                              hipStream_t stream) {
    const float* input_state = (const float*)d_in[0];
    const int*   adj         = (const int*)  d_in[1];
    const float* node_mask   = (const float*)d_in[2];
    const float* query_vec   = (const float*)d_in[3];
    const float* W_type      = (const float*)d_in[4];
    const float* a_type      = (const float*)d_in[5];
    const float* qattn_W1    = (const float*)d_in[6];
    const float* qattn_W2    = (const float*)d_in[7];
    float* out = (float*)d_out;

    // workspace layout (~25 MB; previous rounds confirmed ws >= 57 MB)
    float* ws   = (float*)d_ws;
    float* t1   = ws;                 // 76800 f
    float* ssrc = t1   + 76800;       // 65536 f
    float* sdst = ssrc + 65536;       // 65536 f
    unsigned short* W3T_hi = (unsigned short*)(sdst + 65536);   // 102400 u16
    unsigned short* W3T_lo = W3T_hi + 320 * 320;                // 102400 u16
    unsigned short* GTh    = W3T_lo + 320 * 320;                // 81920 u16
    unsigned short* GTl    = GTh + 4 * 64 * 320;                // 81920 u16
    unsigned short* UTh    = GTl + 4 * 64 * 320;                // 163840 u16
    unsigned short* UTl    = UTh + 32 * 16 * 320;               // 163840 u16
    unsigned short* hmT_hi = UTl + 32 * 16 * 320;               // 5242880 u16
    unsigned short* hmT_lo = hmT_hi + (size_t)Nn * CPAD * Ee;   // 5242880 u16
    float* t1p = (float*)(hmT_lo + (size_t)Nn * CPAD * Ee);     // 307200 f
    float* gp  = t1p + 307200;                                  // 307200 f

    hipLaunchKernelGGL(prep_kernel, dim3(640), dim3(256), 0, stream,
                       W_type + 3 * DIN * DOUT, W3T_hi, W3T_lo, UTh, UTl, GTh, GTl);
    hipLaunchKernelGGL(gates1_part_kernel, dim3(75, NT, 4), dim3(256), 0, stream,
                       query_vec, qattn_W1, t1p);
    hipLaunchKernelGGL(gates1_fin_kernel, dim3(75, NT), dim3(256), 0, stream,
                       t1p, t1);
    hipLaunchKernelGGL(gates2_part_kernel, dim3(75, NT, 4), dim3(256), 0, stream,
                       t1, qattn_W2, gp);
    hipLaunchKernelGGL(gates2_fin_kernel, dim3(75, NT), dim3(256), 0, stream,
                       gp, a_type, GTh, GTl);
    hipLaunchKernelGGL(uvec_mfma_kernel, dim3(5, NT), dim3(256), 0, stream,
                       W_type, GTh, GTl, UTh, UTl);
    hipLaunchKernelGGL(hm_mfma_kernel, dim3((Nn * Ee) / 32), dim3(256), 0, stream,
                       input_state, node_mask, W3T_hi, W3T_lo, UTh, UTl,
                       hmT_hi, hmT_lo, ssrc, sdst);
    hipLaunchKernelGGL(attn8_kernel, dim3(512), dim3(512), 0, stream,
                       adj, ssrc, sdst, hmT_hi, hmT_lo, out);
}